// Round 1
// 17368.425 us; speedup vs baseline: 1.0019x; 1.0019x over previous
//
#include <hip/hip_runtime.h>
#include <cstdint>
#include <cstddef>

// Problem constants: L=2, T=512, B=32, I=H=512
#define TT   512
#define BB   32
#define HH   512
#define KK   512
#define QS   16777216   // quantity stride = L*T*B*H
#define LTBH 8388608    // per-layer stride = T*B*H
#define NBLK 16         // workgroups per layer
#define RING 65536      // per-layer h ring: 4*BB*HH shorts

typedef __attribute__((ext_vector_type(8))) __bf16 bf16x8;
typedef __attribute__((ext_vector_type(8))) short  s16x8;
typedef __attribute__((ext_vector_type(4))) short  s16x4;
typedef __attribute__((ext_vector_type(4))) float  f32x4;
typedef __attribute__((ext_vector_type(2))) unsigned long long u64x2;

#define MFMA(a, b, c) c = __builtin_amdgcn_mfma_f32_16x16x32_bf16(a, b, c, 0, 0, 0)

static __device__ __forceinline__ unsigned short f2bf_rne(float f) {
  unsigned u = __float_as_uint(f);
  u += 0x7fffu + ((u >> 16) & 1u);
  return (unsigned short)(u >> 16);
}

// 8 consecutive fp32 -> bf16x8 fragment (truncation; error << absmax threshold)
static __device__ __forceinline__ bf16x8 load_f32_bf8(const float* __restrict__ p) {
  uint4 a = *(const uint4*)p;
  uint4 b = *(const uint4*)(p + 4);
  s16x8 r;
  r[0] = (short)(a.x >> 16); r[1] = (short)(a.y >> 16);
  r[2] = (short)(a.z >> 16); r[3] = (short)(a.w >> 16);
  r[4] = (short)(b.x >> 16); r[5] = (short)(b.y >> 16);
  r[6] = (short)(b.z >> 16); r[7] = (short)(b.w >> 16);
  return __builtin_bit_cast(bf16x8, r);
}

// normal cached load (read-only data: weights, x)
static __device__ __forceinline__ bf16x8 load_bf8(const short* __restrict__ p) {
  return __builtin_bit_cast(bf16x8, *(const s16x8*)p);
}

// cross-block-communicated data: relaxed agent atomics -> global_load sc0 sc1
// (bypasses stale L1/L2, NO buffer_inv emitted)
static __device__ __forceinline__ bf16x8 load_bf8_agent(const short* p) {
  u64x2 v;
  v[0] = __hip_atomic_load((const unsigned long long*)p,
                           __ATOMIC_RELAXED, __HIP_MEMORY_SCOPE_AGENT);
  v[1] = __hip_atomic_load((const unsigned long long*)(p + 4),
                           __ATOMIC_RELAXED, __HIP_MEMORY_SCOPE_AGENT);
  return __builtin_bit_cast(bf16x8, v);
}

static __device__ __forceinline__ void spin_ge(int* p, int tgt) {
  while (__hip_atomic_load(p, __ATOMIC_RELAXED, __HIP_MEMORY_SCOPE_AGENT) < tgt)
    __builtin_amdgcn_s_sleep(1);
}

static __device__ __forceinline__ float fsig(float x) {
  return __builtin_amdgcn_rcpf(1.0f + __expf(-x));
}
static __device__ __forceinline__ float ftanh(float x) {
  return 2.0f * __builtin_amdgcn_rcpf(1.0f + __expf(-2.0f * x)) - 1.0f;
}

__global__ void zero_kernel(int* __restrict__ p, int n) {
  int i = blockIdx.x * 256 + threadIdx.x;
  if (i < n) p[i] = 0;
}

// fp32 weights -> bf16 (RNE), vectorized x4
__global__ void wconv_kernel(const float* __restrict__ s, short* __restrict__ d, int n4) {
  int i = blockIdx.x * 256 + threadIdx.x;
  if (i < n4) {
    uint4 v = ((const uint4*)s)[i];
    s16x4 o;
    o[0] = (short)f2bf_rne(__uint_as_float(v.x));
    o[1] = (short)f2bf_rne(__uint_as_float(v.y));
    o[2] = (short)f2bf_rne(__uint_as_float(v.z));
    o[3] = (short)f2bf_rne(__uint_as_float(v.w));
    ((s16x4*)d)[i] = o;
  }
}

// Persistent scan: 32 blocks = 2 layers x 16 j-slice workgroups.
// All cross-block traffic (h ring, counters) uses relaxed agent-scope atomics
// (sc0/sc1 bypass of the non-coherent per-XCD L2) -> NO buffer_wbl2/buffer_inv
// anywhere in the step loop. Weights/x stay L2-resident.
// h ring is depth-4 per layer; layer 1 reads layer 0's ring (slot (t+1)&3);
// layer 0 guard-waits cnt1 >= (t-3)*NBLK so it can't lap the ring.
__global__ __launch_bounds__(256, 1) void lstm_scan_all(
    const float* __restrict__ x,
    const short* __restrict__ wihb,   // [L][2048][512] bf16
    const short* __restrict__ whhb,   // [L][2048][512] bf16
    const float* __restrict__ bihg,   // [L][2048]
    const float* __restrict__ bhhg,   // [L][2048]
    float* __restrict__ out,          // [6][L][T][B][H]
    short* __restrict__ hring,        // [L][4][B][H] bf16 ring
    int* __restrict__ cnt)            // [L][32] barrier counters (128B apart)
{
  __shared__ float gsm[4][32][33];   // [gate q][b][jj], padded
  __shared__ float csm[32][33];      // c state, padded
  __shared__ float biasm[4][32];

  const int layer = blockIdx.x >> 4;
  const int w     = blockIdx.x & 15;
  const int j0    = w * 32;
  const int tid   = threadIdx.x;
  const int wave  = tid >> 6;        // wave == gate type q (i,f,g,o)
  const int lane  = tid & 63;
  const int l16   = lane & 15;
  const int kg    = lane >> 4;       // k-group 0..3
  const int koff  = kg * 8;

  const short* __restrict__ wih = wihb + (size_t)layer * (4 * HH * KK);
  const short* __restrict__ whh = whhb + (size_t)layer * (4 * HH * KK);
  float* __restrict__ outb = out + (size_t)layer * LTBH;
  short* __restrict__ ring0  = hring;                 // layer-0 ring
  short* __restrict__ myring = hring + layer * RING;
  int* __restrict__ mycnt  = cnt + layer * 32;
  int* __restrict__ cnt0   = cnt;
  int* __restrict__ cnt1   = cnt + 32;

  for (int idx = tid; idx < 32 * 33; idx += 256) (&csm[0][0])[idx] = 0.0f;
  if (tid < 128) {
    int q = tid >> 5, jj = tid & 31;
    biasm[q][jj] = bihg[layer * 2048 + q * 512 + j0 + jj]
                 + bhhg[layer * 2048 + q * 512 + j0 + jj];
  }
  __syncthreads();

  // B-operand rows for this wave's two 16-col n-tiles (global gate rows)
  const int gb = wave * 512 + j0;
  const short* __restrict__ wi0 = wih + (size_t)(gb      + l16) * KK + koff;
  const short* __restrict__ wi1 = wih + (size_t)(gb + 16 + l16) * KK + koff;
  const short* __restrict__ wh0 = whh + (size_t)(gb      + l16) * KK + koff;
  const short* __restrict__ wh1 = whh + (size_t)(gb + 16 + l16) * KK + koff;

  const int actb = tid >> 3;         // activation: thread owns (b, jj0..jj0+3)
  const int actj = (tid & 7) * 4;

  for (int t = 0; t < TT; ++t) {
    // --- all waits up front: relaxed polls only, zero cache maintenance ---
    if (tid == 0) {
      if (layer == 1) {
        spin_ge(cnt0, (t + 1) * NBLK);       // h0[t] published by layer 0
      } else if (t >= 4) {
        spin_ge(cnt1, (t - 3) * NBLK);       // ring anti-overwrite guard
      }
      if (t) spin_ge(mycnt, t * NBLK);       // own-layer h(t) published
    }
    __syncthreads();

    f32x4 a00 = {0.f, 0.f, 0.f, 0.f}, a01 = a00, a10 = a00, a11 = a00;

    // x-part: gates += A_t @ Wih^T
    if (layer == 0) {
      const float* __restrict__ xr0 = x + (size_t)t * (BB * KK) + (size_t)l16 * KK + koff;
      const float* __restrict__ xr1 = xr0 + 16 * KK;
#pragma unroll 4
      for (int kc = 0; kc < KK; kc += 32) {
        bf16x8 fa0 = load_f32_bf8(xr0 + kc);
        bf16x8 fa1 = load_f32_bf8(xr1 + kc);
        bf16x8 fb0 = load_bf8(wi0 + kc);
        bf16x8 fb1 = load_bf8(wi1 + kc);
        MFMA(fa0, fb0, a00); MFMA(fa0, fb1, a01);
        MFMA(fa1, fb0, a10); MFMA(fa1, fb1, a11);
      }
    } else {
      // layer-1 input = h0[t] from layer-0 ring slot (t+1)&3, bf16 RNE
      const short* xr0 = ring0 + ((t + 1) & 3) * (BB * HH) + l16 * HH + koff;
      const short* xr1 = xr0 + 16 * HH;
#pragma unroll 4
      for (int kc = 0; kc < KK; kc += 32) {
        bf16x8 fa0 = load_bf8_agent(xr0 + kc);
        bf16x8 fa1 = load_bf8_agent(xr1 + kc);
        bf16x8 fb0 = load_bf8(wi0 + kc);
        bf16x8 fb1 = load_bf8(wi1 + kc);
        MFMA(fa0, fb0, a00); MFMA(fa0, fb1, a01);
        MFMA(fa1, fb0, a10); MFMA(fa1, fb1, a11);
      }
    }

    // h-part: gates += h_{t-1} @ Whh^T   (own ring slot t&3)
    {
      const short* hr0 = myring + (t & 3) * (BB * HH) + l16 * HH + koff;
      const short* hr1 = hr0 + 16 * HH;
#pragma unroll 4
      for (int kc = 0; kc < HH; kc += 32) {
        bf16x8 fa0 = load_bf8_agent(hr0 + kc);
        bf16x8 fa1 = load_bf8_agent(hr1 + kc);
        bf16x8 fb0 = load_bf8(wh0 + kc);
        bf16x8 fb1 = load_bf8(wh1 + kc);
        MFMA(fa0, fb0, a00); MFMA(fa0, fb1, a01);
        MFMA(fa1, fb0, a10); MFMA(fa1, fb1, a11);
      }
    }

    // C/D layout: col = lane&15, row = (lane>>4)*4 + reg
    const int r0 = kg * 4;
#pragma unroll
    for (int r = 0; r < 4; ++r) {
      gsm[wave][r0 + r][l16]           = a00[r];
      gsm[wave][r0 + r][16 + l16]      = a01[r];
      gsm[wave][16 + r0 + r][l16]      = a10[r];
      gsm[wave][16 + r0 + r][16 + l16] = a11[r];
    }
    __syncthreads();

    {
      f32x4 vh, vc, vi, vf, vg, vo;
      s16x4 hnext;
#pragma unroll
      for (int u = 0; u < 4; ++u) {
        const int jj = actj + u;
        float gi = gsm[0][actb][jj] + biasm[0][jj];
        float gf = gsm[1][actb][jj] + biasm[1][jj];
        float gg = gsm[2][actb][jj] + biasm[2][jj];
        float go = gsm[3][actb][jj] + biasm[3][jj];
        float iv = fsig(gi), fv = fsig(gf), gv = ftanh(gg), ov = fsig(go);
        float cv = fv * csm[actb][jj] + iv * gv;
        csm[actb][jj] = cv;
        float hv = ov * ftanh(cv);
        vh[u] = hv; vc[u] = cv; vi[u] = iv; vf[u] = fv; vg[u] = gv; vo[u] = ov;
        hnext[u] = (short)f2bf_rne(hv);
      }
      float* __restrict__ po = outb + (size_t)t * (BB * HH) + (size_t)actb * HH + j0 + actj;
      *(f32x4*)(po)               = vh;
      *(f32x4*)(po + (size_t)QS)      = vc;
      *(f32x4*)(po + (size_t)2 * QS)  = vi;
      *(f32x4*)(po + (size_t)3 * QS)  = vf;
      *(f32x4*)(po + (size_t)4 * QS)  = vg;
      *(f32x4*)(po + (size_t)5 * QS)  = vo;
      // publish h(t+1) to own ring slot (t+1)&3 via sc0/sc1 store (no wbl2)
      __hip_atomic_store(
          (unsigned long long*)(myring + ((t + 1) & 3) * (BB * HH) + actb * HH + j0 + actj),
          __builtin_bit_cast(unsigned long long, hnext),
          __ATOMIC_RELAXED, __HIP_MEMORY_SCOPE_AGENT);
    }

    // drain stores to the coherence point, then arrive (relaxed RMW, no wbl2)
    asm volatile("s_waitcnt vmcnt(0)" ::: "memory");
    __syncthreads();
    if (tid == 0)
      __hip_atomic_fetch_add(mycnt, 1, __ATOMIC_RELAXED, __HIP_MEMORY_SCOPE_AGENT);
  }
}

extern "C" void kernel_launch(void* const* d_in, const int* in_sizes, int n_in,
                              void* d_out, int out_size, void* d_ws, size_t ws_size,
                              hipStream_t stream) {
  const float* x    = (const float*)d_in[0];
  const float* w_ih = (const float*)d_in[1];
  const float* w_hh = (const float*)d_in[2];
  const float* b_ih = (const float*)d_in[3];
  const float* b_hh = (const float*)d_in[4];
  float* out = (float*)d_out;

  // ws layout: wih_bf16 4MB | whh_bf16 4MB | hring 256KB | cnt 256B (~8.4 MB)
  short* wihb  = (short*)d_ws;
  short* whhb  = wihb + 2097152;   // L*2048*512
  short* hring = whhb + 2097152;
  int*   cnt   = (int*)(hring + 131072);  // L*4*B*H shorts

  // zero h ring + barrier counters (ws is poisoned each call)
  zero_kernel<<<(65600 + 255) / 256, 256, 0, stream>>>((int*)hring, 65536 + 64);
  // one-time weight conversion to bf16 (RNE)
  wconv_kernel<<<2048, 256, 0, stream>>>(w_ih, wihb, 524288);
  wconv_kernel<<<2048, 256, 0, stream>>>(w_hh, whhb, 524288);
  // pipelined 2-layer persistent scan
  lstm_scan_all<<<32, 256, 0, stream>>>(x, wihb, whhb, b_ih, b_hh, out, hring, cnt);
}